// Round 1
// baseline (32193.076 us; speedup 1.0000x reference)
//
#include <hip/hip_runtime.h>

#define NWG 64
#define NTHR 512
#define SEQ 2048

typedef __attribute__((ext_vector_type(8))) short short8;
typedef __attribute__((ext_vector_type(4))) float f32x4;

__device__ inline short f2bf(float f) {
  union { float f; unsigned u; } v; v.f = f;
  unsigned r = v.u + 0x7FFFu + ((v.u >> 16) & 1u);
  return (short)(r >> 16);
}

__device__ inline float sigm(float x) { return 1.f / (1.f + __expf(-x)); }
__device__ inline float tanh_(float x) { float e = __expf(2.f * x); return 1.f - 2.f / (e + 1.f); }

// coherent 16B ring read: two agent-scope relaxed u64 loads (bypass stale L1/L2,
// read the device coherence point) -> no acquire fence needed anywhere.
__device__ inline short8 ringld(const short* p) {
  const unsigned long long* q = (const unsigned long long*)p;
  unsigned long long lo = __hip_atomic_load(q,     __ATOMIC_RELAXED, __HIP_MEMORY_SCOPE_AGENT);
  unsigned long long hi = __hip_atomic_load(q + 1, __ATOMIC_RELAXED, __HIP_MEMORY_SCOPE_AGENT);
  union { unsigned long long u[2]; short8 s; } v;
  v.u[0] = lo; v.u[1] = hi;
  return v.s;
}

__global__ void __launch_bounds__(NTHR) lstm_kern(
    const float* __restrict__ X,
    const float* __restrict__ Wih,
    const float* __restrict__ Whh,
    const float* __restrict__ bih,
    const float* __restrict__ bhh,
    float* __restrict__ out,
    unsigned* __restrict__ flags,
    short* __restrict__ h1r,
    short* __restrict__ h2r) {
  // Per-WG: 16 hidden units -> 64 gate cols {g*512 + u0 + j, j<16}, K=1024 ([x;h])
  __shared__ short Wlds[64][1032];   // W^T bf16: [col_loc][k], k<512 ih, >=512 hh
  __shared__ float bsum[64];
  __shared__ float glds[64][36];     // gate pre-acts, col-major; stride 36 keeps f32x4 aligned, 2-way banks

  const int tid = threadIdx.x;
  const int wg = blockIdx.x;
  const int layer = wg >> 5;           // 32 WGs per layer
  const int u0 = (wg & 31) * 16;       // first hidden unit of this WG

  // ---- one-time: stage weights (bf16) + fused bias into LDS ----
  {
    const int col_loc = tid >> 3;      // 0..63
    const int l8 = tid & 7;
    const int cg = (col_loc >> 4) * 512 + u0 + (col_loc & 15);
    const float* wi = Wih + ((size_t)layer * 2048 + cg) * 512;
    const float* wh = Whh + ((size_t)layer * 2048 + cg) * 512;
    for (int k0 = l8 * 4; k0 < 512; k0 += 32) {
      float4 a = *(const float4*)(wi + k0);
      Wlds[col_loc][k0 + 0] = f2bf(a.x); Wlds[col_loc][k0 + 1] = f2bf(a.y);
      Wlds[col_loc][k0 + 2] = f2bf(a.z); Wlds[col_loc][k0 + 3] = f2bf(a.w);
      float4 b = *(const float4*)(wh + k0);
      Wlds[col_loc][512 + k0 + 0] = f2bf(b.x); Wlds[col_loc][512 + k0 + 1] = f2bf(b.y);
      Wlds[col_loc][512 + k0 + 2] = f2bf(b.z); Wlds[col_loc][512 + k0 + 3] = f2bf(b.w);
    }
    if (tid < 64) {
      const int cg2 = (tid >> 4) * 512 + u0 + (tid & 15);
      bsum[tid] = bih[layer * 2048 + cg2] + bhh[layer * 2048 + cg2];
    }
  }
  __syncthreads();

  // MFMA mapping (16x16x32 bf16): A[m=lane&15][k=quad*8+j]; D: col(lane&15)=gate, row(quad*4+reg)=batch
  const int lane = tid & 63;
  const int wid = tid >> 6;            // 0..7
  const int col = lane & 15;
  const int quad = lane >> 4;
  const int mi = wid & 1;              // batch tile (16 rows)
  const int ni = wid >> 1;             // gate-col tile (16 cols)
  const int m = mi * 16 + col;         // batch row for A
  const int nc = ni * 16 + col;        // local gate col for B/D
  const int kj = quad * 8;

  // elementwise: one cell per thread: unit eu (0..15), batch eb (0..31)
  const int eu = tid & 15;
  const int eb = tid >> 4;
  float cst = 0.f;

  short* wring = layer ? h2r : h1r;
  unsigned* wringu = (unsigned*)wring;
  const short* hring = layer ? h2r : h1r;   // own-layer h for hh part

  // accp = input-projection partial for THIS iteration's step (software pipeline)
  f32x4 accp = {0.f, 0.f, 0.f, 0.f};
  if (layer == 0) {
    const float* xrow = X + (size_t)m * SEQ * 512 + kj;   // t = 0
    #pragma unroll
    for (int s = 0; s < 16; ++s) {
      const float* xp = xrow + s * 32;
      float4 f0 = *(const float4*)xp;
      float4 f1 = *(const float4*)(xp + 4);
      short8 a;
      a[0] = f2bf(f0.x); a[1] = f2bf(f0.y); a[2] = f2bf(f0.z); a[3] = f2bf(f0.w);
      a[4] = f2bf(f1.x); a[5] = f2bf(f1.y); a[6] = f2bf(f1.z); a[7] = f2bf(f1.w);
      short8 b = *(const short8*)&Wlds[nc][s * 32 + kj];
      accp = __builtin_amdgcn_mfma_f32_16x16x32_bf16(a, b, accp, 0, 0, 0);
    }
  }

  // layer 0 computes t=p; layer 1 lags 2: t=p-2 (ring distance 2 < depth 4)
  for (int p = 0; p <= SEQ + 1; ++p) {
    const int tt = layer ? (p - 2) : p;
    const bool active = (tt >= 0) && (tt < SEQ);

    if (active) {
      f32x4 acc = accp;
      if (tt > 0) {   // hh part: the only inter-barrier-dependent compute
        const short* hrow = hring + ((size_t)((tt - 1) & 3) * 32 + m) * 512 + kj;
        #pragma unroll
        for (int s = 0; s < 16; ++s) {
          short8 a = ringld(hrow + s * 32);
          short8 b = *(const short8*)&Wlds[nc][512 + s * 32 + kj];
          acc = __builtin_amdgcn_mfma_f32_16x16x32_bf16(a, b, acc, 0, 0, 0);
        }
      }
      const float bsv = bsum[nc];
      float4 gv;
      gv.x = acc[0] + bsv; gv.y = acc[1] + bsv; gv.z = acc[2] + bsv; gv.w = acc[3] + bsv;
      *(float4*)&glds[nc][mi * 16 + quad * 4] = gv;
    }
    __syncthreads();
    if (active) {
      const float gi = glds[eu][eb];
      const float gf = glds[16 + eu][eb];
      const float gg = glds[32 + eu][eb];
      const float go = glds[48 + eu][eb];
      cst = sigm(gf) * cst + sigm(gi) * tanh_(gg);
      const float h = sigm(go) * tanh_(cst);
      // pack bf16 pair (eu, eu^1) via shfl; even-eu lane stores u32 write-through
      const int hu = (int)(unsigned short)f2bf(h);
      const int other = __shfl_xor(hu, 1);
      if ((eu & 1) == 0) {
        const unsigned pk = (unsigned)hu | ((unsigned)other << 16);
        __hip_atomic_store(&wringu[((size_t)(tt & 3) * 32 + eb) * 256 + (u0 >> 1) + (eu >> 1)],
                           pk, __ATOMIC_RELAXED, __HIP_MEMORY_SCOPE_AGENT);
      }
      if (layer) {
        out[((size_t)eb * SEQ + tt) * 512 + u0 + eu] = h;
      }
    }
    __syncthreads();   // drains vmcnt: ring stores are device-visible past here
    if (tid == 0) {
      __hip_atomic_store(&flags[wg], (unsigned)(p + 1),
                         __ATOMIC_RELAXED, __HIP_MEMORY_SCOPE_AGENT);
    }

    // ---- input-projection for NEXT iteration, in the barrier-wait shadow ----
    // layer 0: X@Wih for t=p+1 (X always available, L2-cached: no fence anymore)
    // layer 1: h1@Wih for t=p-1 (h1r[p-1] was flagged at p, confirmed by LAST poll;
    //          slot (p-1)&3 is not overwritten until L0's iter p+3, which requires
    //          our flag >= p+3 -> cannot precede this read)
    f32x4 anew = {0.f, 0.f, 0.f, 0.f};
    if (layer == 0) {
      const int nt = p + 1;
      if (nt < SEQ) {
        const float* xrow = X + ((size_t)m * SEQ + nt) * 512 + kj;
        #pragma unroll
        for (int s = 0; s < 16; ++s) {
          const float* xp = xrow + s * 32;
          float4 f0 = *(const float4*)xp;
          float4 f1 = *(const float4*)(xp + 4);
          short8 a;
          a[0] = f2bf(f0.x); a[1] = f2bf(f0.y); a[2] = f2bf(f0.z); a[3] = f2bf(f0.w);
          a[4] = f2bf(f1.x); a[5] = f2bf(f1.y); a[6] = f2bf(f1.z); a[7] = f2bf(f1.w);
          short8 b = *(const short8*)&Wlds[nc][s * 32 + kj];
          anew = __builtin_amdgcn_mfma_f32_16x16x32_bf16(a, b, anew, 0, 0, 0);
        }
      }
    } else {
      const int nt = p - 1;
      if (nt >= 0 && nt < SEQ) {
        const short* xr = h1r + ((size_t)(nt & 3) * 32 + m) * 512 + kj;
        #pragma unroll
        for (int s = 0; s < 16; ++s) {
          short8 a = ringld(xr + s * 32);
          short8 b = *(const short8*)&Wlds[nc][s * 32 + kj];
          anew = __builtin_amdgcn_mfma_f32_16x16x32_bf16(a, b, anew, 0, 0, 0);
        }
      }
    }
    accp = anew;

    // ---- distributed-flag grid barrier (64 flags = 4 cachelines) ----
    if (p <= SEQ) {
      const unsigned tgt = (unsigned)(p + 1);
      int done;
      do {
        int ok = 1;
        if (tid < NWG) {
          const unsigned f = __hip_atomic_load(&flags[tid], __ATOMIC_RELAXED,
                                               __HIP_MEMORY_SCOPE_AGENT);
          ok = (int)(f >= tgt);
        }
        done = __syncthreads_and(ok);
      } while (!done);
      __builtin_amdgcn_sched_barrier(0);  // keep ring reads after the poll
    }
  }
}

extern "C" void kernel_launch(void* const* d_in, const int* in_sizes, int n_in,
                              void* d_out, int out_size, void* d_ws, size_t ws_size,
                              hipStream_t stream) {
  const float* X   = (const float*)d_in[0];
  const float* Wih = (const float*)d_in[1];
  const float* Whh = (const float*)d_in[2];
  const float* bih = (const float*)d_in[3];
  const float* bhh = (const float*)d_in[4];
  float* out = (float*)d_out;
  char* ws = (char*)d_ws;

  unsigned* flags = (unsigned*)ws;                       // 64 dwords (1 KB reserved)
  short* h1r = (short*)(ws + 1024);                      // [4][32][512] bf16 ring
  short* h2r = (short*)(ws + 1024 + 4 * 32 * 512 * 2);   // [4][32][512] bf16 ring

  hipMemsetAsync(ws, 0, 1024, stream);  // zero flags every launch

  void* args[] = {(void*)&X, (void*)&Wih, (void*)&Whh, (void*)&bih, (void*)&bhh,
                  (void*)&out, (void*)&flags, (void*)&h1r, (void*)&h2r};
  hipLaunchCooperativeKernel((void*)lstm_kern, dim3(NWG), dim3(NTHR), args, 0, stream);
}

// Round 2
// 27975.266 us; speedup vs baseline: 1.1508x; 1.1508x over previous
//
#include <hip/hip_runtime.h>

#define NWG 64
#define NTHR 512
#define SEQ 2048

typedef __attribute__((ext_vector_type(8))) short short8;
typedef __attribute__((ext_vector_type(4))) float f32x4;

__device__ inline short f2bf(float f) {
  union { float f; unsigned u; } v; v.f = f;
  unsigned r = v.u + 0x7FFFu + ((v.u >> 16) & 1u);
  return (short)(r >> 16);
}

__device__ inline float sigm(float x) { return 1.f / (1.f + __expf(-x)); }
__device__ inline float tanh_(float x) { float e = __expf(2.f * x); return 1.f - 2.f / (e + 1.f); }

__global__ void __launch_bounds__(NTHR) lstm_kern(
    const float* __restrict__ X,
    const float* __restrict__ Wih,
    const float* __restrict__ Whh,
    const float* __restrict__ bih,
    const float* __restrict__ bhh,
    float* __restrict__ out,
    unsigned* __restrict__ flags,
    short* __restrict__ h1r,
    short* __restrict__ h2r) {
  // Per-WG: 16 hidden units -> 64 gate cols {g*512 + u0 + j, j<16}, K=1024 ([x;h])
  __shared__ short Wlds[64][1032];   // W^T bf16: [col_loc][k], k<512 ih, >=512 hh
  __shared__ float bsum[64];
  __shared__ float glds[64][36];     // gate pre-acts, col-major

  const int tid = threadIdx.x;
  const int wg = blockIdx.x;
  const int layer = wg >> 5;           // 32 WGs per layer
  const int u0 = (wg & 31) * 16;       // first hidden unit of this WG

  // ---- one-time: stage weights (bf16) + fused bias into LDS ----
  {
    const int col_loc = tid >> 3;      // 0..63
    const int l8 = tid & 7;
    const int cg = (col_loc >> 4) * 512 + u0 + (col_loc & 15);
    const float* wi = Wih + ((size_t)layer * 2048 + cg) * 512;
    const float* wh = Whh + ((size_t)layer * 2048 + cg) * 512;
    for (int k0 = l8 * 4; k0 < 512; k0 += 32) {
      float4 a = *(const float4*)(wi + k0);
      Wlds[col_loc][k0 + 0] = f2bf(a.x); Wlds[col_loc][k0 + 1] = f2bf(a.y);
      Wlds[col_loc][k0 + 2] = f2bf(a.z); Wlds[col_loc][k0 + 3] = f2bf(a.w);
      float4 b = *(const float4*)(wh + k0);
      Wlds[col_loc][512 + k0 + 0] = f2bf(b.x); Wlds[col_loc][512 + k0 + 1] = f2bf(b.y);
      Wlds[col_loc][512 + k0 + 2] = f2bf(b.z); Wlds[col_loc][512 + k0 + 3] = f2bf(b.w);
    }
    if (tid < 64) {
      const int cg2 = (tid >> 4) * 512 + u0 + (tid & 15);
      bsum[tid] = bih[layer * 2048 + cg2] + bhh[layer * 2048 + cg2];
    }
  }
  __syncthreads();

  // MFMA mapping (16x16x32 bf16): A[m=lane&15][k=quad*8+j]; D: col(lane&15)=gate, row(quad*4+reg)=batch
  const int lane = tid & 63;
  const int wid = tid >> 6;            // 0..7
  const int col = lane & 15;
  const int quad = lane >> 4;
  const int mi = wid & 1;              // batch tile (16 rows)
  const int ni = wid >> 1;             // gate-col tile (16 cols)
  const int m = mi * 16 + col;         // batch row for A
  const int nc = ni * 16 + col;        // local gate col for B/D
  const int kj = quad * 8;

  // elementwise: one cell per thread: unit eu (0..15), batch eb (0..31)
  const int eu = tid & 15;
  const int eb = tid >> 4;
  float cst = 0.f;

  short* wring = layer ? h2r : h1r;
  unsigned* wringu = (unsigned*)wring;
  const short* hring = layer ? h2r : h1r;   // own-layer h for hh part

  // accp = input-projection partial for THIS iteration's step (software pipeline)
  f32x4 accp = {0.f, 0.f, 0.f, 0.f};
  if (layer == 0) {
    const float* xrow = X + (size_t)m * SEQ * 512 + kj;   // t = 0
    #pragma unroll
    for (int s = 0; s < 16; ++s) {
      const float* xp = xrow + s * 32;
      float4 f0 = *(const float4*)xp;
      float4 f1 = *(const float4*)(xp + 4);
      short8 a;
      a[0] = f2bf(f0.x); a[1] = f2bf(f0.y); a[2] = f2bf(f0.z); a[3] = f2bf(f0.w);
      a[4] = f2bf(f1.x); a[5] = f2bf(f1.y); a[6] = f2bf(f1.z); a[7] = f2bf(f1.w);
      short8 b = *(const short8*)&Wlds[nc][s * 32 + kj];
      accp = __builtin_amdgcn_mfma_f32_16x16x32_bf16(a, b, accp, 0, 0, 0);
    }
  }

  // layer 0 computes t=p; layer 1 lags 2: t=p-2 (ring distance 2 < depth 4)
  for (int p = 0; p <= SEQ + 1; ++p) {
    const int tt = layer ? (p - 2) : p;
    const bool active = (tt >= 0) && (tt < SEQ);

    if (active) {
      f32x4 acc = accp;
      if (tt > 0) {   // hh part: the only inter-barrier-dependent compute
        // plain vector loads (L1-cacheable, coalesced); coherence by the
        // acquire-agent fence after the last poll. Hoist all 16 A-frags
        // into registers -> one LLC latency burst, then pure MFMA chain.
        const short* hrow = hring + ((size_t)((tt - 1) & 3) * 32 + m) * 512 + kj;
        short8 a[16];
        #pragma unroll
        for (int s = 0; s < 16; ++s) a[s] = *(const short8*)(hrow + s * 32);
        #pragma unroll
        for (int s = 0; s < 16; ++s) {
          short8 b = *(const short8*)&Wlds[nc][512 + s * 32 + kj];
          acc = __builtin_amdgcn_mfma_f32_16x16x32_bf16(a[s], b, acc, 0, 0, 0);
        }
      }
      const float bsv = bsum[nc];
      float4 gv;
      gv.x = acc[0] + bsv; gv.y = acc[1] + bsv; gv.z = acc[2] + bsv; gv.w = acc[3] + bsv;
      *(float4*)&glds[nc][mi * 16 + quad * 4] = gv;
    }
    __syncthreads();
    if (active) {
      const float gi = glds[eu][eb];
      const float gf = glds[16 + eu][eb];
      const float gg = glds[32 + eu][eb];
      const float go = glds[48 + eu][eb];
      cst = sigm(gf) * cst + sigm(gi) * tanh_(gg);
      const float h = sigm(go) * tanh_(cst);
      // pack bf16 pair (eu, eu^1) via shfl; even-eu lane stores u32 write-through
      const int hu = (int)(unsigned short)f2bf(h);
      const int other = __shfl_xor(hu, 1);
      if ((eu & 1) == 0) {
        const unsigned pk = (unsigned)hu | ((unsigned)other << 16);
        __hip_atomic_store(&wringu[((size_t)(tt & 3) * 32 + eb) * 256 + (u0 >> 1) + (eu >> 1)],
                           pk, __ATOMIC_RELAXED, __HIP_MEMORY_SCOPE_AGENT);
      }
      if (layer) {
        out[((size_t)eb * SEQ + tt) * 512 + u0 + eu] = h;
      }
    }
    __syncthreads();   // drains vmcnt: ring stores are device-visible past here
    if (tid == 0) {
      __hip_atomic_store(&flags[wg], (unsigned)(p + 1),
                         __ATOMIC_RELAXED, __HIP_MEMORY_SCOPE_AGENT);
    }

    // ---- input-projection for NEXT iteration, in the barrier-wait shadow ----
    // layer 0: X@Wih for t=p+1 (X cached; its lines die at the next fence,
    //          but the result is already in accp registers)
    // layer 1: h1@Wih for t=p-1. h1r[p-1] was flagged with value p, confirmed
    //          by the poll at end of iter p-1, and the acquire fence after that
    //          poll invalidated any stale copy of slot (p-1)&3 (last touched
    //          at iter p-4, with 4 fences in between). Slot isn't overwritten
    //          until L0's iter p+3 (needs our flag >= p+3).
    f32x4 anew = {0.f, 0.f, 0.f, 0.f};
    if (layer == 0) {
      const int nt = p + 1;
      if (nt < SEQ) {
        const float* xrow = X + ((size_t)m * SEQ + nt) * 512 + kj;
        #pragma unroll
        for (int s = 0; s < 16; ++s) {
          const float* xp = xrow + s * 32;
          float4 f0 = *(const float4*)xp;
          float4 f1 = *(const float4*)(xp + 4);
          short8 a;
          a[0] = f2bf(f0.x); a[1] = f2bf(f0.y); a[2] = f2bf(f0.z); a[3] = f2bf(f0.w);
          a[4] = f2bf(f1.x); a[5] = f2bf(f1.y); a[6] = f2bf(f1.z); a[7] = f2bf(f1.w);
          short8 b = *(const short8*)&Wlds[nc][s * 32 + kj];
          anew = __builtin_amdgcn_mfma_f32_16x16x32_bf16(a, b, anew, 0, 0, 0);
        }
      }
    } else {
      const int nt = p - 1;
      if (nt >= 0 && nt < SEQ) {
        const short* xr = h1r + ((size_t)(nt & 3) * 32 + m) * 512 + kj;
        short8 a[16];
        #pragma unroll
        for (int s = 0; s < 16; ++s) a[s] = *(const short8*)(xr + s * 32);
        #pragma unroll
        for (int s = 0; s < 16; ++s) {
          short8 b = *(const short8*)&Wlds[nc][s * 32 + kj];
          anew = __builtin_amdgcn_mfma_f32_16x16x32_bf16(a[s], b, anew, 0, 0, 0);
        }
      }
    }
    accp = anew;

    // ---- distributed-flag grid barrier (64 flags = 4 cachelines) ----
    if (p <= SEQ) {
      const unsigned tgt = (unsigned)(p + 1);
      int done;
      do {
        int ok = 1;
        if (tid < NWG) {
          const unsigned f = __hip_atomic_load(&flags[tid], __ATOMIC_RELAXED,
                                               __HIP_MEMORY_SCOPE_AGENT);
          ok = (int)(f >= tgt);
        }
        done = __syncthreads_and(ok);
      } while (!done);
      // one invalidation per step: ring reads above the next barrier see fresh data
      __builtin_amdgcn_fence(__ATOMIC_ACQUIRE, "agent");
      __builtin_amdgcn_sched_barrier(0);
    }
  }
}

extern "C" void kernel_launch(void* const* d_in, const int* in_sizes, int n_in,
                              void* d_out, int out_size, void* d_ws, size_t ws_size,
                              hipStream_t stream) {
  const float* X   = (const float*)d_in[0];
  const float* Wih = (const float*)d_in[1];
  const float* Whh = (const float*)d_in[2];
  const float* bih = (const float*)d_in[3];
  const float* bhh = (const float*)d_in[4];
  float* out = (float*)d_out;
  char* ws = (char*)d_ws;

  unsigned* flags = (unsigned*)ws;                       // 64 dwords (1 KB reserved)
  short* h1r = (short*)(ws + 1024);                      // [4][32][512] bf16 ring
  short* h2r = (short*)(ws + 1024 + 4 * 32 * 512 * 2);   // [4][32][512] bf16 ring

  hipMemsetAsync(ws, 0, 1024, stream);  // zero flags every launch

  void* args[] = {(void*)&X, (void*)&Wih, (void*)&Whh, (void*)&bih, (void*)&bhh,
                  (void*)&out, (void*)&flags, (void*)&h1r, (void*)&h2r};
  hipLaunchCooperativeKernel((void*)lstm_kern, dim3(NWG), dim3(NTHR), args, 0, stream);
}